// Round 3
// baseline (137.398 us; speedup 1.0000x reference)
//
#include <hip/hip_runtime.h>

#define NROW 32768
#define KCODE 1024

typedef short bf16x8 __attribute__((ext_vector_type(8)));
typedef float floatx4 __attribute__((ext_vector_type(4)));

typedef __attribute__((address_space(1))) const unsigned short g_u16;
typedef __attribute__((address_space(3))) unsigned short l_u16;

// fp32 -> bf16 round-to-nearest-even (finite inputs)
static __device__ __forceinline__ unsigned short f2bf(float f) {
  unsigned int x = __float_as_uint(f);
  x += 0x7fffu + ((x >> 16) & 1u);
  return (unsigned short)(x >> 16);
}

// KA: blocks 0..511  : x [32][256][1024] f32 -> xb [N][C] bf16 (transpose) + xn2[n] = sum x^2 (fp32)
//     blocks 512..575: emb -> eb bf16 + hn[k] = 0.5*||e_k||^2 ; block 512 zeroes the loss slot
__global__ __launch_bounds__(256) void k_prep(const float* __restrict__ x,
                                              const float* __restrict__ emb,
                                              unsigned short* __restrict__ xb,
                                              float* __restrict__ xn2,
                                              unsigned short* __restrict__ eb,
                                              float* __restrict__ hn,
                                              float* __restrict__ loss) {
  __shared__ unsigned short tile[256 * 66];  // stride 66 shorts -> 33 dwords (odd): <=4-way banks
  __shared__ float xred[256];
  const int t = threadIdx.x;
  const int bid = blockIdx.x;
  if (bid < 512) {
    const int b = bid >> 4, ht = bid & 15;
    const int hw0 = ht << 6;
    const int n0 = (b << 10) + hw0;
    const int hw_l = t & 63, cs = t >> 6;
    float ss = 0.f;
    const float* xp = x + (((b << 8) + cs) << 10) + hw0 + hw_l;
    for (int i = 0; i < 64; ++i) {            // c = i*4 + cs, coalesced 256B segments along hw
      const int c = (i << 2) + cs;
      const float v = xp[(size_t)i << 12];
      ss += v * v;
      tile[c * 66 + hw_l] = f2bf(v);
    }
    xred[t] = ss;
    __syncthreads();
    if (t < 64) xn2[n0 + t] = xred[t] + xred[t + 64] + xred[t + 128] + xred[t + 192];
    // phase 2: write xb coalesced along c (4B = 2 bf16 per thread)
    const int c2 = (t & 127) * 2, hs = t >> 7;
    for (int i = 0; i < 32; ++i) {
      const int row = (i << 1) + hs;
      const unsigned int u0 = tile[c2 * 66 + row];
      const unsigned int u1 = tile[(c2 + 1) * 66 + row];
      *(unsigned int*)(xb + (((size_t)(n0 + row)) << 8) + c2) = u0 | (u1 << 16);
    }
  } else {
    if (bid == 512 && t == 0) *loss = 0.f;   // KC (later dispatch) is the only reader/adder
    const int w = t >> 6, lane = t & 63;
    const int kb = ((bid - 512) << 4) + (w << 2);
    for (int jj = 0; jj < 4; ++jj) {
      const int k = kb + jj;
      const float* er = emb + (k << 8);
      unsigned short* eo = eb + (k << 8);
      float ss = 0.f;
      for (int j = 0; j < 4; ++j) {
        const float v = er[j * 64 + lane];
        ss += v * v;
        eo[j * 64 + lane] = f2bf(v);
      }
      for (int off = 32; off >= 1; off >>= 1) ss += __shfl_xor(ss, off, 64);
      if (lane == 0) hn[k] = 0.5f * ss;
    }
  }
}

// KB: per row argmax_k ( x_n . e_k - 0.5||e_k||^2 ) over a 256-code quarter.
// 4 waves x 64 rows/wave (A-frags register-resident), grid 512 = 128 rb x 4 q
// -> 2 blocks/CU, 8 waves/CU. E-tiles staged via global_load_lds (16B) into a
// double buffer, ONE barrier per tile: DMA for tile kt+1 flies during MFMA on kt.
// GLL dest is lane-contiguous, so conflict-avoidance moves to an XOR swizzle of
// the global SOURCE chunk: physical chunk pc = c16 ^ (code&7)  (readers: 8 lanes
// per 4-bank group = 2/bank/phase = free).
__global__ __launch_bounds__(256, 2) void k_argmax(const unsigned short* __restrict__ xb,
                                                   const unsigned short* __restrict__ eb,
                                                   const float* __restrict__ hn,
                                                   float* __restrict__ pval,
                                                   int* __restrict__ pidx) {
  __shared__ unsigned short es[2][64 * 256];  // 2 x 32 KB, linear (GLL order)
  __shared__ float hn_l[256];
  const int t = threadIdx.x;
  const int w = t >> 6, lane = t & 63;
  const int r16 = lane & 15, quad = lane >> 4;
  const int s7 = r16 & 7;                     // read-side swizzle key (row&7)
  const int rb = blockIdx.x >> 2, q = blockIdx.x & 3;
  const int n0 = rb << 8;          // 256 rows/block
  const int kbase = q << 8;        // 256 codes/block

  // per-thread GLL source offset (shorts), independent of instr index i:
  //   code_low = t>>5 (3b), c16 = (t&31) ^ (t>>5)
  const int soff = ((t >> 5) << 8) + ((((t & 31) ^ (t >> 5))) << 3);
  const int doff = (w << 6) << 3;  // wave-uniform LDS chunk base (shorts) for i=0

  // stage tile 0 into buf 0 (DMA starts before anything else)
  {
    const unsigned short* ebt = eb + ((size_t)kbase << 8) + soff;
    for (int i = 0; i < 8; ++i)
      __builtin_amdgcn_global_load_lds((g_u16*)(ebt + (i << 11)),
                                       (l_u16*)&es[0][doff + (i << 11)], 16, 0, 0);
  }

  hn_l[t] = hn[kbase + t];

  // A fragments: 4 row-groups of 16, rows n0 + w*64 + rg*16 + r16, k-chunk quad*8 (+ci*32)
  bf16x8 a[4][8];
  for (int rg = 0; rg < 4; ++rg) {
    const unsigned short* xr = xb + (((size_t)(n0 + (w << 6) + (rg << 4) + r16)) << 8) + (quad << 3);
    for (int ci = 0; ci < 8; ++ci) a[rg][ci] = *(const bf16x8*)(xr + (ci << 5));
  }

  float bv[4][4]; int bi[4][4];
  for (int rg = 0; rg < 4; ++rg)
    for (int r = 0; r < 4; ++r) { bv[rg][r] = -3.4e38f; bi[rg][r] = 0; }

  for (int kt = 0; kt < 4; ++kt) {
    __syncthreads();   // drains this wave's GLLs (tile kt landed) + closes reads of other buf
    if (kt < 3) {      // launch DMA for tile kt+1: in flight across the whole MFMA loop
      const unsigned short* ebt = eb + (((size_t)(kbase + ((kt + 1) << 6))) << 8) + soff;
      unsigned short* dst = &es[(kt + 1) & 1][doff];
      for (int i = 0; i < 8; ++i)
        __builtin_amdgcn_global_load_lds((g_u16*)(ebt + (i << 11)),
                                         (l_u16*)(dst + (i << 11)), 16, 0, 0);
    }
    const unsigned short* buf = es[kt & 1];
    for (int n16 = 0; n16 < 4; ++n16) {
      floatx4 acc0 = {0.f,0.f,0.f,0.f}, acc1 = {0.f,0.f,0.f,0.f};
      floatx4 acc2 = {0.f,0.f,0.f,0.f}, acc3 = {0.f,0.f,0.f,0.f};
      const unsigned short* base_r = buf + (((n16 << 4) + r16) << 8);
      for (int ci = 0; ci < 8; ++ci) {
        const int pc = ((quad + (ci << 2)) ^ s7) & 31;          // physical 16B chunk
        const bf16x8 bfr = *(const bf16x8*)(base_r + (pc << 3)); // 1 read feeds 4 MFMAs
        acc0 = __builtin_amdgcn_mfma_f32_16x16x32_bf16(a[0][ci], bfr, acc0, 0, 0, 0);
        acc1 = __builtin_amdgcn_mfma_f32_16x16x32_bf16(a[1][ci], bfr, acc1, 0, 0, 0);
        acc2 = __builtin_amdgcn_mfma_f32_16x16x32_bf16(a[2][ci], bfr, acc2, 0, 0, 0);
        acc3 = __builtin_amdgcn_mfma_f32_16x16x32_bf16(a[3][ci], bfr, acc3, 0, 0, 0);
      }
      const int kloc = (kt << 6) + (n16 << 4) + r16;
      const float h = hn_l[kloc];
      const int kglob = kbase + kloc;
      for (int r = 0; r < 4; ++r) {           // D: row = quad*4 + r, col(code) = r16
        float v;
        v = acc0[r] - h; if (v > bv[0][r]) { bv[0][r] = v; bi[0][r] = kglob; }
        v = acc1[r] - h; if (v > bv[1][r]) { bv[1][r] = v; bi[1][r] = kglob; }
        v = acc2[r] - h; if (v > bv[2][r]) { bv[2][r] = v; bi[2][r] = kglob; }
        v = acc3[r] - h; if (v > bv[3][r]) { bv[3][r] = v; bi[3][r] = kglob; }
      }
    }
  }
  // reduce across the 16 code-columns (stays within each 16-lane group)
  for (int off = 8; off >= 1; off >>= 1)
    for (int rg = 0; rg < 4; ++rg)
      for (int r = 0; r < 4; ++r) {
        const float ov = __shfl_xor(bv[rg][r], off, 64);
        const int   oi = __shfl_xor(bi[rg][r], off, 64);
        if (ov > bv[rg][r] || (ov == bv[rg][r] && oi < bi[rg][r])) { bv[rg][r] = ov; bi[rg][r] = oi; }
      }
  if (r16 == 0) {
    for (int rg = 0; rg < 4; ++rg) {
      const int base = q * NROW + n0 + (w << 6) + (rg << 4) + (quad << 2);
      for (int r = 0; r < 4; ++r) { pval[base + r] = bv[rg][r]; pidx[base + r] = bi[rg][r]; }
    }
  }
}

// KC: merge 4 quarters -> idx; gather winning code rows into LDS (coalesced); write out [B,C,H,W];
// loss = 1.25/(N*C) * sum_n (xn2[n] - 2*v*_n)   (no x re-read)
__global__ __launch_bounds__(256) void k_output(const float* __restrict__ emb,
                                                const float* __restrict__ pval,
                                                const int* __restrict__ pidx,
                                                const float* __restrict__ xn2,
                                                float* __restrict__ out,
                                                float* __restrict__ loss) {
  __shared__ float sel[64 * 257];
  __shared__ int idx_l[64];
  const int t = threadIdx.x;
  const int w = t >> 6, lane = t & 63;
  const int n0 = blockIdx.x << 6;          // 64 rows/block
  const int b = n0 >> 10, hw0 = n0 & 1023;
  float lv = 0.f;
  if (t < 64) {                            // wave 0 exactly
    const int n = n0 + t;
    float vm = pval[n]; int im = pidx[n];
    for (int qq = 1; qq < 4; ++qq) {       // ascending k: strict > keeps lowest index on ties
      const float v = pval[qq * NROW + n];
      if (v > vm) { vm = v; im = pidx[qq * NROW + n]; }
    }
    idx_l[t] = im;
    lv = xn2[n] - 2.f * vm;                // = ||x_n - e_{im}||^2
  }
  __syncthreads();
  for (int i = 0; i < 16; ++i) {
    const int row = (w << 4) + i;
    const float* er = emb + ((size_t)idx_l[row] << 8);
    for (int j = 0; j < 4; ++j)
      sel[row * 257 + (j << 6) + lane] = er[(j << 6) + lane];  // coalesced 256B loads from L2
  }
  if (t < 64) {                            // wave-0 loss reduce + one atomic per block
    for (int off = 32; off >= 1; off >>= 1) lv += __shfl_xor(lv, off, 64);
    if (t == 0) atomicAdd(loss, lv * (1.25f / 8388608.0f));
  }
  __syncthreads();
  // write out: float4 along hw (16B/lane), 256B segments per c
  const int hwq = t & 15, cg = t >> 4;
  const size_t base = ((size_t)b << 18);   // b*256*1024
  for (int it = 0; it < 16; ++it) {
    const int c = (it << 4) + cg;
    float4 v;
    v.x = sel[(hwq * 4 + 0) * 257 + c];
    v.y = sel[(hwq * 4 + 1) * 257 + c];
    v.z = sel[(hwq * 4 + 2) * 257 + c];
    v.w = sel[(hwq * 4 + 3) * 257 + c];
    *(float4*)(out + base + ((size_t)c << 10) + hw0 + (hwq << 2)) = v;
  }
}

extern "C" void kernel_launch(void* const* d_in, const int* in_sizes, int n_in,
                              void* d_out, int out_size, void* d_ws, size_t ws_size,
                              hipStream_t stream) {
  const float* x   = (const float*)d_in[0];
  const float* emb = (const float*)d_in[1];
  float* out  = (float*)d_out;
  float* loss = out + 8388608;

  char* ws = (char*)d_ws;
  unsigned short* xb = (unsigned short*)(ws);              // 16,777,216 B
  unsigned short* eb = (unsigned short*)(ws + 16777216);   //    524,288 B
  float* hn   = (float*)(ws + 17301504);                   //      4,096 B
  float* xn2  = (float*)(ws + 17305600);                   //    131,072 B
  float* pval = (float*)(ws + 17436672);                   //    524,288 B
  int*   pidx = (int*)  (ws + 17960960);                   //    524,288 B

  k_prep<<<576, 256, 0, stream>>>(x, emb, xb, xn2, eb, hn, loss);
  k_argmax<<<512, 256, 0, stream>>>(xb, eb, hn, pval, pidx);
  k_output<<<512, 256, 0, stream>>>(emb, pval, pidx, xn2, out, loss);
}

// Round 4
// 134.323 us; speedup vs baseline: 1.0229x; 1.0229x over previous
//
#include <hip/hip_runtime.h>

#define NROW 32768
#define KCODE 1024

typedef short bf16x8 __attribute__((ext_vector_type(8)));
typedef float floatx4 __attribute__((ext_vector_type(4)));

// fp32 -> bf16 round-to-nearest-even (finite inputs)
static __device__ __forceinline__ unsigned short f2bf(float f) {
  unsigned int x = __float_as_uint(f);
  x += 0x7fffu + ((x >> 16) & 1u);
  return (unsigned short)(x >> 16);
}

// KA: blocks 0..511  : x [32][256][1024] f32 -> xb [N][C] bf16 (transpose) + xn2[n] = sum x^2 (fp32)
//     blocks 512..575: emb -> eb bf16 + hn[k] = 0.5*||e_k||^2 ; block 512 zeroes the loss slot
__global__ __launch_bounds__(256) void k_prep(const float* __restrict__ x,
                                              const float* __restrict__ emb,
                                              unsigned short* __restrict__ xb,
                                              float* __restrict__ xn2,
                                              unsigned short* __restrict__ eb,
                                              float* __restrict__ hn,
                                              float* __restrict__ loss) {
  __shared__ unsigned short tile[256 * 66];  // stride 66 shorts -> 33 dwords (odd): <=4-way banks
  __shared__ float xred[256];
  const int t = threadIdx.x;
  const int bid = blockIdx.x;
  if (bid < 512) {
    const int b = bid >> 4, ht = bid & 15;
    const int hw0 = ht << 6;
    const int n0 = (b << 10) + hw0;
    const int hw_l = t & 63, cs = t >> 6;
    float ss = 0.f;
    const float* xp = x + (((b << 8) + cs) << 10) + hw0 + hw_l;
    for (int i = 0; i < 64; ++i) {            // c = i*4 + cs, coalesced 256B segments along hw
      const int c = (i << 2) + cs;
      const float v = xp[(size_t)i << 12];
      ss += v * v;
      tile[c * 66 + hw_l] = f2bf(v);
    }
    xred[t] = ss;
    __syncthreads();
    if (t < 64) xn2[n0 + t] = xred[t] + xred[t + 64] + xred[t + 128] + xred[t + 192];
    // phase 2: write xb coalesced along c (4B = 2 bf16 per thread)
    const int c2 = (t & 127) * 2, hs = t >> 7;
    for (int i = 0; i < 32; ++i) {
      const int row = (i << 1) + hs;
      const unsigned int u0 = tile[c2 * 66 + row];
      const unsigned int u1 = tile[(c2 + 1) * 66 + row];
      *(unsigned int*)(xb + (((size_t)(n0 + row)) << 8) + c2) = u0 | (u1 << 16);
    }
  } else {
    if (bid == 512 && t == 0) *loss = 0.f;   // KC (later dispatch) is the only reader/adder
    const int w = t >> 6, lane = t & 63;
    const int kb = ((bid - 512) << 4) + (w << 2);
    for (int jj = 0; jj < 4; ++jj) {
      const int k = kb + jj;
      const float* er = emb + (k << 8);
      unsigned short* eo = eb + (k << 8);
      float ss = 0.f;
      for (int j = 0; j < 4; ++j) {
        const float v = er[j * 64 + lane];
        ss += v * v;
        eo[j * 64 + lane] = f2bf(v);
      }
      for (int off = 32; off >= 1; off >>= 1) ss += __shfl_xor(ss, off, 64);
      if (lane == 0) hn[k] = 0.5f * ss;
    }
  }
}

// KB: per row argmax_k ( x_n . e_k - 0.5||e_k||^2 ) over a 256-code quarter.
// 256 thr = 4 waves x 64 rows/wave (A-frags resident: reuse 4 per ds_read_b128),
// grid 512 = 128 row-blocks x 4 quarters -> 2 blocks/CU, 8 waves/CU.
// Next E-tile prefetched into VGPRs so staging overlaps the MFMA loop.
// NOTE (R3 post-mortem): KB's floor is the bf16 MFMA ceiling itself
// (17.2 GFLOP / 2075 TF = 8.3 us); a GLL double-buffer restructure measured
// +2.5 us vs this version -- staging is NOT the bottleneck here. Keep as-is.
__global__ __launch_bounds__(256, 2) void k_argmax(const unsigned short* __restrict__ xb,
                                                   const unsigned short* __restrict__ eb,
                                                   const float* __restrict__ hn,
                                                   float* __restrict__ pval,
                                                   int* __restrict__ pidx) {
  __shared__ unsigned short es[64 * 264];  // 64 codes x 256 c, stride 264: uniform bank spread
  __shared__ float hn_l[256];
  const int t = threadIdx.x;
  const int w = t >> 6, lane = t & 63;
  const int r16 = lane & 15, quad = lane >> 4;
  const int rb = blockIdx.x >> 2, q = blockIdx.x & 3;
  const int n0 = rb << 8;          // 256 rows/block
  const int kbase = q << 8;        // 256 codes/block

  hn_l[t] = hn[kbase + t];

  // A fragments: 4 row-groups of 16, rows n0 + w*64 + rg*16 + r16, k-chunk quad*8 (+ci*32)
  bf16x8 a[4][8];
  for (int rg = 0; rg < 4; ++rg) {
    const unsigned short* xr = xb + (((size_t)(n0 + (w << 6) + (rg << 4) + r16)) << 8) + (quad << 3);
    for (int ci = 0; ci < 8; ++ci) a[rg][ci] = *(const bf16x8*)(xr + (ci << 5));
  }

  const int goffb = ((t >> 5) << 8) + ((t & 31) << 3);   // global tile offset (shorts)
  const int loffb = (t >> 5) * 264 + ((t & 31) << 3);    // LDS tile offset (shorts)
  bf16x8 pf[8];
  {
    const unsigned short* ebt = eb + ((size_t)kbase << 8) + goffb;
    for (int i = 0; i < 8; ++i) pf[i] = *(const bf16x8*)(ebt + i * 2048);
  }

  float bv[4][4]; int bi[4][4];
  for (int rg = 0; rg < 4; ++rg)
    for (int r = 0; r < 4; ++r) { bv[rg][r] = -3.4e38f; bi[rg][r] = 0; }

  for (int kt = 0; kt < 4; ++kt) {
    __syncthreads();                          // previous tile fully consumed
    for (int i = 0; i < 8; ++i) *(bf16x8*)(&es[loffb + i * (8 * 264)]) = pf[i];
    __syncthreads();
    if (kt < 3) {                             // prefetch next tile: overlaps the MFMA loop
      const unsigned short* ebt = eb + (((size_t)(kbase + ((kt + 1) << 6))) << 8) + goffb;
      for (int i = 0; i < 8; ++i) pf[i] = *(const bf16x8*)(ebt + i * 2048);
    }
    for (int n16 = 0; n16 < 4; ++n16) {
      floatx4 acc0 = {0.f,0.f,0.f,0.f}, acc1 = {0.f,0.f,0.f,0.f};
      floatx4 acc2 = {0.f,0.f,0.f,0.f}, acc3 = {0.f,0.f,0.f,0.f};
      const unsigned short* esr = &es[((n16 << 4) + r16) * 264 + (quad << 3)];
      for (int ci = 0; ci < 8; ++ci) {
        const bf16x8 bfr = *(const bf16x8*)(esr + (ci << 5));  // 1 read feeds 4 MFMAs
        acc0 = __builtin_amdgcn_mfma_f32_16x16x32_bf16(a[0][ci], bfr, acc0, 0, 0, 0);
        acc1 = __builtin_amdgcn_mfma_f32_16x16x32_bf16(a[1][ci], bfr, acc1, 0, 0, 0);
        acc2 = __builtin_amdgcn_mfma_f32_16x16x32_bf16(a[2][ci], bfr, acc2, 0, 0, 0);
        acc3 = __builtin_amdgcn_mfma_f32_16x16x32_bf16(a[3][ci], bfr, acc3, 0, 0, 0);
      }
      const int kloc = (kt << 6) + (n16 << 4) + r16;
      const float h = hn_l[kloc];
      const int kglob = kbase + kloc;
      for (int r = 0; r < 4; ++r) {           // D: row = quad*4 + r, col(code) = r16
        float v;
        v = acc0[r] - h; if (v > bv[0][r]) { bv[0][r] = v; bi[0][r] = kglob; }
        v = acc1[r] - h; if (v > bv[1][r]) { bv[1][r] = v; bi[1][r] = kglob; }
        v = acc2[r] - h; if (v > bv[2][r]) { bv[2][r] = v; bi[2][r] = kglob; }
        v = acc3[r] - h; if (v > bv[3][r]) { bv[3][r] = v; bi[3][r] = kglob; }
      }
    }
  }
  // reduce across the 16 code-columns (stays within each 16-lane group)
  for (int off = 8; off >= 1; off >>= 1)
    for (int rg = 0; rg < 4; ++rg)
      for (int r = 0; r < 4; ++r) {
        const float ov = __shfl_xor(bv[rg][r], off, 64);
        const int   oi = __shfl_xor(bi[rg][r], off, 64);
        if (ov > bv[rg][r] || (ov == bv[rg][r] && oi < bi[rg][r])) { bv[rg][r] = ov; bi[rg][r] = oi; }
      }
  if (r16 == 0) {
    for (int rg = 0; rg < 4; ++rg) {
      const int base = q * NROW + n0 + (w << 6) + (rg << 4) + (quad << 2);
      for (int r = 0; r < 4; ++r) { pval[base + r] = bv[rg][r]; pidx[base + r] = bi[rg][r]; }
    }
  }
}

// KC: merge 4 quarters -> idx; gather winning code rows into LDS (coalesced); write out [B,C,H,W];
// loss = 1.25/(N*C) * sum_n (xn2[n] - 2*v*_n)   (no x re-read)
__global__ __launch_bounds__(256) void k_output(const float* __restrict__ emb,
                                                const float* __restrict__ pval,
                                                const int* __restrict__ pidx,
                                                const float* __restrict__ xn2,
                                                float* __restrict__ out,
                                                float* __restrict__ loss) {
  __shared__ float sel[64 * 257];
  __shared__ int idx_l[64];
  const int t = threadIdx.x;
  const int w = t >> 6, lane = t & 63;
  const int n0 = blockIdx.x << 6;          // 64 rows/block
  const int b = n0 >> 10, hw0 = n0 & 1023;
  float lv = 0.f;
  if (t < 64) {                            // wave 0 exactly
    const int n = n0 + t;
    float vm = pval[n]; int im = pidx[n];
    for (int qq = 1; qq < 4; ++qq) {       // ascending k: strict > keeps lowest index on ties
      const float v = pval[qq * NROW + n];
      if (v > vm) { vm = v; im = pidx[qq * NROW + n]; }
    }
    idx_l[t] = im;
    lv = xn2[n] - 2.f * vm;                // = ||x_n - e_{im}||^2
  }
  __syncthreads();
  for (int i = 0; i < 16; ++i) {
    const int row = (w << 4) + i;
    const float* er = emb + ((size_t)idx_l[row] << 8);
    for (int j = 0; j < 4; ++j)
      sel[row * 257 + (j << 6) + lane] = er[(j << 6) + lane];  // coalesced 256B loads from L2
  }
  if (t < 64) {                            // wave-0 loss reduce + one atomic per block
    for (int off = 32; off >= 1; off >>= 1) lv += __shfl_xor(lv, off, 64);
    if (t == 0) atomicAdd(loss, lv * (1.25f / 8388608.0f));
  }
  __syncthreads();
  // write out: float4 along hw (16B/lane), 256B segments per c
  const int hwq = t & 15, cg = t >> 4;
  const size_t base = ((size_t)b << 18);   // b*256*1024
  for (int it = 0; it < 16; ++it) {
    const int c = (it << 4) + cg;
    float4 v;
    v.x = sel[(hwq * 4 + 0) * 257 + c];
    v.y = sel[(hwq * 4 + 1) * 257 + c];
    v.z = sel[(hwq * 4 + 2) * 257 + c];
    v.w = sel[(hwq * 4 + 3) * 257 + c];
    *(float4*)(out + base + ((size_t)c << 10) + hw0 + (hwq << 2)) = v;
  }
}

extern "C" void kernel_launch(void* const* d_in, const int* in_sizes, int n_in,
                              void* d_out, int out_size, void* d_ws, size_t ws_size,
                              hipStream_t stream) {
  const float* x   = (const float*)d_in[0];
  const float* emb = (const float*)d_in[1];
  float* out  = (float*)d_out;
  float* loss = out + 8388608;

  char* ws = (char*)d_ws;
  unsigned short* xb = (unsigned short*)(ws);              // 16,777,216 B
  unsigned short* eb = (unsigned short*)(ws + 16777216);   //    524,288 B
  float* hn   = (float*)(ws + 17301504);                   //      4,096 B
  float* xn2  = (float*)(ws + 17305600);                   //    131,072 B
  float* pval = (float*)(ws + 17436672);                   //    524,288 B
  int*   pidx = (int*)  (ws + 17960960);                   //    524,288 B

  k_prep<<<576, 256, 0, stream>>>(x, emb, xb, xn2, eb, hn, loss);
  k_argmax<<<512, 256, 0, stream>>>(xb, eb, hn, pval, pidx);
  k_output<<<512, 256, 0, stream>>>(emb, pval, pidx, xn2, out, loss);
}